// Round 3
// baseline (429.606 us; speedup 1.0000x reference)
//
#include <hip/hip_runtime.h>

#define NQ 32768
#define NP 8192
#define FD 32
#define KNN 8
#define QB 128          // queries per block
#define TB 256          // threads per block (2 threads per query)
#define CH 1024         // points staged per half per chunk

__global__ __launch_bounds__(TB) void knn_kernel(
    const float* __restrict__ xyz, const float* __restrict__ points,
    const float* __restrict__ feats, float* __restrict__ out)
{
#pragma clang fp contract(off)   // replicate numpy's per-op f32 rounding exactly
    __shared__ float4 sp[2 * CH];   // 32 KB, reused for merge scratch later

    const int t    = threadIdx.x;
    const int lq   = t & (QB - 1);
    const int half = t >> 7;                 // 0: points [0,4096), 1: [4096,8192)
    const int q    = blockIdx.x * QB + lq;

    const float qx = xyz[q * 3 + 0];
    const float qy = xyz[q * 3 + 1];
    const float qz = xyz[q * 3 + 2];
    // np: sum(xyz*xyz, -1): rounded squares, sequential add — NO fma
    const float qxx = qx * qx, qyy = qy * qy, qzz = qz * qz;
    const float qn  = (qxx + qyy) + qzz;

    float bd[KNN]; int bi[KNN];
#pragma unroll
    for (int j = 0; j < KNN; ++j) { bd[j] = __builtin_inff(); bi[j] = 0; }

    const int pbase0 = half * (NP / 2);

    for (int c = 0; c < (NP / 2) / CH; ++c) {
        __syncthreads();
        // stage: sp[0..CH) <- half-0 chunk, sp[CH..2CH) <- half-1 chunk
        for (int i = t; i < 2 * CH; i += TB) {
            int hh = i >> 10;
            int pi = hh * (NP / 2) + c * CH + (i & (CH - 1));
            float px = points[pi * 3 + 0];
            float py = points[pi * 3 + 1];
            float pz = points[pi * 3 + 2];
            // np: sum(points*points, -1): rounded squares, sequential add — NO fma
            float pxx = px * px, pyy = py * py, pzz = pz * pz;
            float pn  = (pxx + pyy) + pzz;
            sp[i] = make_float4(px, py, pz, pn);
        }
        __syncthreads();

        const float4* spp = sp + half * CH;
        const int ib0 = pbase0 + c * CH;
#pragma unroll 4
        for (int i = 0; i < CH; ++i) {
            float4 p = spp[i];                        // wave-uniform -> broadcast
            // np sgemm (OpenBLAS, K=3): acc = round(a0*b0); acc = fma(a1,b1,acc); acc = fma(a2,b2,acc)
            float dot = __builtin_fmaf(qz, p.z, __builtin_fmaf(qy, p.y, qx * p.x));
            // np: (qn - 2.0*dot) + pn, left-assoc; 2*dot exact
            float d2 = (qn - 2.0f * dot) + p.w;
            if (__builtin_expect(d2 < bd[KNN - 1], 0)) {
                bool c0[KNN];
#pragma unroll
                for (int j = 0; j < KNN; ++j) c0[j] = d2 < bd[j];   // strict: ties keep lower idx
#pragma unroll
                for (int j = KNN - 1; j > 0; --j) {
                    bd[j] = c0[j] ? (c0[j - 1] ? bd[j - 1] : d2) : bd[j];
                    bi[j] = c0[j] ? (c0[j - 1] ? bi[j - 1] : (ib0 + i)) : bi[j];
                }
                if (c0[0]) { bd[0] = d2; bi[0] = ib0 + i; }
            }
        }
    }

    __syncthreads();
    // ---- merge the two half-lists per query via LDS ----
    float* md  = (float*)sp;                 // [TB*KNN] distances
    int*   mi  = ((int*)sp) + TB * KNN;      // [TB*KNN] indices
    int*   fin = ((int*)sp) + 2 * TB * KNN;  // [QB*KNN] final indices
#pragma unroll
    for (int j = 0; j < KNN; ++j) { md[t * KNN + j] = bd[j]; mi[t * KNN + j] = bi[j]; }
    __syncthreads();

    if (t < QB) {   // waves 0,1 fully active: no intra-wave divergence
        const float* dA = md + t * KNN;        const int* iA = mi + t * KNN;
        const float* dB = md + (t + QB) * KNN; const int* iB = mi + (t + QB) * KNN;
        int ia = 0, ib = 0;
#pragma unroll
        for (int j = 0; j < KNN; ++j) {        // ia+ib == j <= 7, no overrun
            float da = dA[ia], db = dB[ib];
            bool tb = db < da;                 // tie -> A (lower index) wins
            int id = tb ? iB[ib] : iA[ia];
            if (tb) ib++; else ia++;
            fin[t * KNN + j] = id;
        }
    }
    __syncthreads();

    // ---- cooperative coalesced gather ----
    // knn_points: [NQ][KNN][3] floats
    const long opb = (long)blockIdx.x * (QB * KNN * 3);
    for (int off = t; off < QB * KNN * 3; off += TB) {
        int qq = off / (KNN * 3);
        int r  = off - qq * (KNN * 3);
        int j  = r / 3;
        int cc = r - j * 3;
        out[opb + off] = points[fin[qq * KNN + j] * 3 + cc];
    }
    // knn_feats: [NQ][KNN][FD] floats, float4-vectorized
    float4* outf4 = (float4*)(out + (long)NQ * KNN * 3 + (long)blockIdx.x * (QB * KNN * FD));
    const float4* feats4 = (const float4*)feats;
    for (int off = t; off < QB * KNN * FD / 4; off += TB) {
        int qq = off >> 6;        // /(KNN*FD/4) = /64
        int r  = off & 63;
        int j  = r >> 3;
        int c4 = r & 7;
        outf4[off] = feats4[fin[qq * KNN + j] * (FD / 4) + c4];
    }
}

extern "C" void kernel_launch(void* const* d_in, const int* in_sizes, int n_in,
                              void* d_out, int out_size, void* d_ws, size_t ws_size,
                              hipStream_t stream) {
    const float* xyz    = (const float*)d_in[0];
    const float* points = (const float*)d_in[1];
    const float* feats  = (const float*)d_in[2];
    float* out = (float*)d_out;
    hipLaunchKernelGGL(knn_kernel, dim3(NQ / QB), dim3(TB), 0, stream,
                       xyz, points, feats, out);
}

// Round 4
// 243.977 us; speedup vs baseline: 1.7608x; 1.7608x over previous
//
#include <hip/hip_runtime.h>

#define NQ 32768
#define NP 8192
#define FD 32
#define KNN 8
#define QB 32           // queries per block
#define SL 8            // point-slices per query (threads per query)
#define TB 256          // QB * SL
#define CHS 256         // points per slice staged per chunk (8 slices * 256 = 2048 float4 = 32KB)
#define NCH 4           // (NP/SL)/CHS chunk iterations

__global__ __launch_bounds__(TB) void knn_kernel(
    const float* __restrict__ xyz, const float* __restrict__ points,
    const float* __restrict__ feats, float* __restrict__ out)
{
#pragma clang fp contract(off)   // replicate numpy's per-op f32 rounding exactly
    __shared__ float4 sp[SL * CHS];   // 32 KB, reused for merge scratch later

    const int t  = threadIdx.x;
    const int lq = t & (QB - 1);      // query within block
    const int sl = t >> 5;            // slice 0..7
    const int q  = blockIdx.x * QB + lq;

    const float qx = xyz[q * 3 + 0];
    const float qy = xyz[q * 3 + 1];
    const float qz = xyz[q * 3 + 2];
    // np: sum(xyz*xyz, -1): rounded squares, sequential add — NO fma
    const float qn = (qx * qx + qy * qy) + qz * qz;

    float bd[KNN]; int bi[KNN];
#pragma unroll
    for (int j = 0; j < KNN; ++j) { bd[j] = __builtin_inff(); bi[j] = 0; }

    for (int c = 0; c < NCH; ++c) {
        __syncthreads();
        // stage: slice k's points [k*1024 + c*256, +256) -> sp[k*256 ...]
        for (int i = t; i < SL * CHS; i += TB) {
            int k  = i >> 8;               // slice of this slot
            int ii = i & (CHS - 1);
            int pi = k * (NP / SL) + c * CHS + ii;
            float px = points[pi * 3 + 0];
            float py = points[pi * 3 + 1];
            float pz = points[pi * 3 + 2];
            // np: sum(points*points, -1): rounded squares, sequential add — NO fma
            float pn = (px * px + py * py) + pz * pz;
            sp[i] = make_float4(px, py, pz, pn);
        }
        __syncthreads();

        const float4* spp = sp + sl * CHS;
        const int ib0 = sl * (NP / SL) + c * CHS;
#pragma unroll 4
        for (int i = 0; i < CHS; ++i) {
            float4 p = spp[i];                        // wave-uniform-ish -> broadcast
            // np sgemm (OpenBLAS, K=3): acc = round(a0*b0); acc = fma(a1,b1,acc); acc = fma(a2,b2,acc)
            float dot = __builtin_fmaf(qz, p.z, __builtin_fmaf(qy, p.y, qx * p.x));
            // np: (qn - 2.0*dot) + pn, left-assoc; 2*dot exact
            float d2 = (qn - 2.0f * dot) + p.w;
            if (__builtin_expect(d2 < bd[KNN - 1], 0)) {
                bool c0[KNN];
#pragma unroll
                for (int j = 0; j < KNN; ++j) c0[j] = d2 < bd[j];   // strict: ties keep lower idx
#pragma unroll
                for (int j = KNN - 1; j > 0; --j) {
                    bd[j] = c0[j] ? (c0[j - 1] ? bd[j - 1] : d2) : bd[j];
                    bi[j] = c0[j] ? (c0[j - 1] ? bi[j - 1] : (ib0 + i)) : bi[j];
                }
                if (c0[0]) { bd[0] = d2; bi[0] = ib0 + i; }
            }
        }
    }

    __syncthreads();
    // ---- merge the 8 slice-lists per query via LDS ----
    // transposed layout [j*TB + t]: conflict-free stores and merge reads
    float* md  = (float*)sp;                  // [KNN*TB] f32 = 8 KB
    int*   mi  = ((int*)sp) + KNN * TB;       // [KNN*TB] int = 8 KB
    int*   fin = ((int*)sp) + 2 * KNN * TB;   // [QB*KNN] int = 1 KB
#pragma unroll
    for (int j = 0; j < KNN; ++j) { md[j * TB + t] = bd[j]; mi[j * TB + t] = bi[j]; }
    __syncthreads();

    if (t < QB) {   // lanes 0..31 of wave 0; strict-< scan in slice order => lower index wins ties
        int h[SL];
#pragma unroll
        for (int s = 0; s < SL; ++s) h[s] = 0;
#pragma unroll
        for (int k = 0; k < KNN; ++k) {
            float best = __builtin_inff(); int bs = 0;
#pragma unroll
            for (int s = 0; s < SL; ++s) {
                float d = md[h[s] * TB + s * QB + t];
                if (d < best) { best = d; bs = s; }
            }
            fin[t * KNN + k] = mi[h[bs] * TB + bs * QB + t];
            h[bs]++;
        }
    }
    __syncthreads();

    // ---- cooperative coalesced gather ----
    // knn_points: [NQ][KNN][3] floats
    const long opb = (long)blockIdx.x * (QB * KNN * 3);
    for (int off = t; off < QB * KNN * 3; off += TB) {
        int qq = off / (KNN * 3);
        int r  = off - qq * (KNN * 3);
        int j  = r / 3;
        int cc = r - j * 3;
        out[opb + off] = points[fin[qq * KNN + j] * 3 + cc];
    }
    // knn_feats: [NQ][KNN][FD] floats, float4-vectorized; 8 consecutive threads
    // read one feats row (128B) contiguously -> coalesced
    float4* outf4 = (float4*)(out + (long)NQ * KNN * 3 + (long)blockIdx.x * (QB * KNN * FD));
    const float4* feats4 = (const float4*)feats;
    for (int off = t; off < QB * KNN * FD / 4; off += TB) {
        int qq = off >> 6;        // /(KNN*FD/4) = /64
        int r  = off & 63;
        int j  = r >> 3;
        int c4 = r & 7;
        outf4[off] = feats4[fin[qq * KNN + j] * (FD / 4) + c4];
    }
}

extern "C" void kernel_launch(void* const* d_in, const int* in_sizes, int n_in,
                              void* d_out, int out_size, void* d_ws, size_t ws_size,
                              hipStream_t stream) {
    const float* xyz    = (const float*)d_in[0];
    const float* points = (const float*)d_in[1];
    const float* feats  = (const float*)d_in[2];
    float* out = (float*)d_out;
    hipLaunchKernelGGL(knn_kernel, dim3(NQ / QB), dim3(TB), 0, stream,
                       xyz, points, feats, out);
}

// Round 5
// 102.489 us; speedup vs baseline: 4.1917x; 2.3805x over previous
//
#include <hip/hip_runtime.h>

#define NQ 32768
#define NP 8192
#define FD 32
#define KNN 8
#define QW 4                 // queries per wave
#define WPB 4                // waves per block
#define TB 256
#define QBLK (QW * WPB)      // 16 queries per block
#define CHP 1024             // points per staged chunk
#define NCH (NP / CHP)       // 8
#define ACH 4                // phase-A chunks (4096 points -> tau bound)
#define CAP 96               // candidate capacity per query (E[cnt]~16)

__global__ __launch_bounds__(TB) void knn_kernel(
    const float* __restrict__ xyz, const float* __restrict__ points,
    const float* __restrict__ feats, float* __restrict__ out)
{
#pragma clang fp contract(off)   // replicate numpy's per-op f32 rounding exactly
    __shared__ float4 sp[CHP];                 // 16 KB point chunk
    __shared__ unsigned skey[QBLK * CAP];      // 6 KB candidate keys
    __shared__ unsigned short sidx16[QBLK * CAP]; // 3 KB candidate indices
    __shared__ int scnt[QBLK];

    const int t     = threadIdx.x;
    const int lane  = t & 63;
    const int wid   = t >> 6;
    const int qbase = blockIdx.x * QBLK + wid * QW;

    if (t < QBLK) scnt[t] = 0;

    float qx[QW], qy[QW], qz[QW], qn[QW];
#pragma unroll
    for (int qq = 0; qq < QW; ++qq) {
        int q = qbase + qq;
        float a = xyz[q * 3 + 0], b = xyz[q * 3 + 1], c = xyz[q * 3 + 2];
        qx[qq] = a; qy[qq] = b; qz[qq] = c;
        // np: rounded squares, sequential add — NO fma
        qn[qq] = (a * a + b * b) + c * c;
    }

    // ---- Phase A: branchless min-scan over chunks 0..ACH-1 ----
    float mn[QW];
#pragma unroll
    for (int qq = 0; qq < QW; ++qq) mn[qq] = __builtin_inff();

    for (int c = 0; c < ACH; ++c) {
        __syncthreads();
        for (int i = t; i < CHP; i += TB) {
            int pi = c * CHP + i;
            float px = points[pi * 3 + 0], py = points[pi * 3 + 1], pz = points[pi * 3 + 2];
            float pn = (px * px + py * py) + pz * pz;   // no fma
            sp[i] = make_float4(px, py, pz, pn);
        }
        __syncthreads();
#pragma unroll 4
        for (int s = 0; s < CHP / 64; ++s) {
            float4 p = sp[s * 64 + lane];
#pragma unroll
            for (int qq = 0; qq < QW; ++qq) {
                // np sgemm K=3: round(a0*b0) then fma chain
                float dot = __builtin_fmaf(qz[qq], p.z, __builtin_fmaf(qy[qq], p.y, qx[qq] * p.x));
                float d2  = (qn[qq] - 2.0f * dot) + p.w;
                mn[qq] = fminf(mn[qq], d2);
            }
        }
    }

    // tau = 8th smallest of the 64 lane-mins (valid upper bound on true 8th-NN d2:
    // the 64 mins are 64 actual d2 values; k-th smallest of a sub-multiset >= k-th of full set)
    float tau[QW];
#pragma unroll
    for (int qq = 0; qq < QW; ++qq) {
        float v = mn[qq];
        for (int k2 = 2; k2 <= 64; k2 <<= 1)
            for (int j = k2 >> 1; j > 0; j >>= 1) {
                float o = __shfl_xor(v, j);
                bool keepMin = ((lane & k2) == 0) == ((lane & j) == 0);
                v = ((o < v) == keepMin) ? o : v;
            }
        tau[qq] = __uint_as_float((unsigned)__builtin_amdgcn_readlane((int)__float_as_uint(v), 7));
    }

    // ---- Phase B: screened scan of all points, append candidates ----
    for (int c = 0; c < NCH; ++c) {
        __syncthreads();
        for (int i = t; i < CHP; i += TB) {
            int pi = c * CHP + i;
            float px = points[pi * 3 + 0], py = points[pi * 3 + 1], pz = points[pi * 3 + 2];
            float pn = (px * px + py * py) + pz * pz;
            sp[i] = make_float4(px, py, pz, pn);
        }
        __syncthreads();
#pragma unroll 2
        for (int s = 0; s < CHP / 64; ++s) {
            float4 p = sp[s * 64 + lane];
            int gidx = c * CHP + s * 64 + lane;
#pragma unroll
            for (int qq = 0; qq < QW; ++qq) {
                float dot = __builtin_fmaf(qz[qq], p.z, __builtin_fmaf(qy[qq], p.y, qx[qq] * p.x));
                float d2  = (qn[qq] - 2.0f * dot) + p.w;
                if (__builtin_expect(d2 <= tau[qq], 0)) {   // <=: keep boundary ties
                    unsigned b = __float_as_uint(d2);
                    unsigned key = (b & 0x80000000u) ? ~b : (b | 0x80000000u); // monotone map
                    int wq = wid * QW + qq;
                    int slot = atomicAdd(&scnt[wq], 1);
                    if (slot >= CAP) slot = CAP - 1;        // impossible-overflow guard
                    skey[wq * CAP + slot] = key;
                    sidx16[wq * CAP + slot] = (unsigned short)gidx;
                }
            }
        }
    }
    __syncthreads();

    // ---- Phase C: exact top-8 per query via u64 bitonic sort of candidates ----
    const float4* feats4 = (const float4*)feats;
    float4* outf4 = (float4*)(out + (long)NQ * KNN * 3);
#pragma unroll
    for (int qq = 0; qq < QW; ++qq) {
        int wq = wid * QW + qq;
        int cnt = scnt[wq];
        unsigned long long key = ~0ull;
        if (lane < cnt) {
            // (mapped d2 << 32) | idx : ascending u64 order == np (value, stable-index) order
            key = ((unsigned long long)skey[wq * CAP + lane] << 32) | sidx16[wq * CAP + lane];
        }
        for (int k2 = 2; k2 <= 64; k2 <<= 1)
            for (int j = k2 >> 1; j > 0; j >>= 1) {
                unsigned lo = __shfl_xor((unsigned)key, j);
                unsigned hi = __shfl_xor((unsigned)(key >> 32), j);
                unsigned long long o = ((unsigned long long)hi << 32) | lo;
                bool keepMin = ((lane & k2) == 0) == ((lane & j) == 0);
                key = ((o < key) == keepMin) ? o : key;
            }
        // lanes 0..7 now hold the top-8 (ascending). Gather outputs.
        int q = qbase + qq;
        // feats: j = lane>>3 selects neighbor, c4 = lane&7 -> fully coalesced 1KB store
        int nb = __shfl((int)(unsigned)key, lane >> 3);
        outf4[(long)q * (KNN * FD / 4) + lane] = feats4[(long)nb * (FD / 4) + (lane & 7)];
        // points: lanes 0..23
        int j2 = lane / 3;
        int nb2 = __shfl((int)(unsigned)key, j2);
        if (lane < 24) {
            out[(long)q * (KNN * 3) + lane] = points[nb2 * 3 + (lane - j2 * 3)];
        }
    }
}

extern "C" void kernel_launch(void* const* d_in, const int* in_sizes, int n_in,
                              void* d_out, int out_size, void* d_ws, size_t ws_size,
                              hipStream_t stream) {
    const float* xyz    = (const float*)d_in[0];
    const float* points = (const float*)d_in[1];
    const float* feats  = (const float*)d_in[2];
    float* out = (float*)d_out;
    hipLaunchKernelGGL(knn_kernel, dim3(NQ / QBLK), dim3(TB), 0, stream,
                       xyz, points, feats, out);
}

// Round 6
// 78.761 us; speedup vs baseline: 5.4546x; 1.3013x over previous
//
#include <hip/hip_runtime.h>

#define NQ 32768
#define NP 8192
#define FD 32
#define KNN 8
#define QW 4                 // queries per wave
#define WPB 4                // waves per block
#define TB 256
#define QBLK (QW * WPB)      // 16 queries per block
#define CHP 1024             // points per staged chunk
#define NCH (NP / CHP)       // 8
#define ACH 4                // phase-A chunks (4096 points -> tau bound)
#define CAP 64               // candidate capacity per query (E[cnt]~20, 10 sigma to 64)

__global__ __launch_bounds__(TB) void knn_kernel(
    const float* __restrict__ xyz, const float* __restrict__ points,
    const float* __restrict__ feats, float* __restrict__ out)
{
#pragma clang fp contract(off)   // np-exact paths use explicit mul/add; fast paths use explicit fmaf
    __shared__ float4 sp[CHP];                    // 16 KB point chunk
    __shared__ unsigned short sidx16[QBLK * CAP]; // 2 KB candidate indices
    __shared__ int scnt[QBLK];

    const int t     = threadIdx.x;
    const int lane  = t & 63;
    const int wid   = t >> 6;
    const int qbase = blockIdx.x * QBLK + wid * QW;

    if (t < QBLK) scnt[t] = 0;

    float qx[QW], qy[QW], qz[QW], qn[QW];
#pragma unroll
    for (int qq = 0; qq < QW; ++qq) {
        int q = qbase + qq;
        float a = xyz[q * 3 + 0], b = xyz[q * 3 + 1], c = xyz[q * 3 + 2];
        qx[qq] = a; qy[qq] = b; qz[qq] = c;
        qn[qq] = (a * a + b * b) + c * c;   // np-exact: rounded squares, sequential add
    }

    // ---- Phase A: branchless min of g = pn - 2*dot (qn cancels; bound-only, fast math ok) ----
    float mn[QW];
#pragma unroll
    for (int qq = 0; qq < QW; ++qq) mn[qq] = __builtin_inff();

    for (int c = 0; c < ACH; ++c) {
        __syncthreads();
        for (int i = t; i < CHP; i += TB) {
            int pi = c * CHP + i;
            float px = points[pi * 3 + 0], py = points[pi * 3 + 1], pz = points[pi * 3 + 2];
            float pn = __builtin_fmaf(pz, pz, __builtin_fmaf(py, py, px * px)); // screen-only norm
            sp[i] = make_float4(px, py, pz, pn);
        }
        __syncthreads();
#pragma unroll 4
        for (int s = 0; s < CHP / 64; ++s) {
            float4 p = sp[s * 64 + lane];
#pragma unroll
            for (int qq = 0; qq < QW; ++qq) {
                float dot = __builtin_fmaf(qz[qq], p.z, __builtin_fmaf(qy[qq], p.y, qx[qq] * p.x));
                float g   = __builtin_fmaf(-2.0f, dot, p.w);
                mn[qq] = fminf(mn[qq], g);
            }
        }
    }

    // tau_g = 8th smallest of the 64 lane-mins (each an actual g-value of a distinct point,
    // so it upper-bounds the 8th-smallest g over the full set). Margin 1e-3 >> max rounding
    // gap (~1.2e-4) between g-path and the np-exact d2 path.
    float tscr[QW];
#pragma unroll
    for (int qq = 0; qq < QW; ++qq) {
        float v = mn[qq];
        for (int k2 = 2; k2 <= 64; k2 <<= 1)
            for (int j = k2 >> 1; j > 0; j >>= 1) {
                float o = __shfl_xor(v, j);
                bool keepMin = ((lane & k2) == 0) == ((lane & j) == 0);
                v = ((o < v) == keepMin) ? o : v;
            }
        float t8 = __uint_as_float((unsigned)__builtin_amdgcn_readlane((int)__float_as_uint(v), 7));
        tscr[qq] = t8 + 1e-3f;
    }

    // ---- Phase B: screened scan of all points; chunk ACH-1 is still resident -> scan first ----
    for (int k = 0; k < NCH; ++k) {
        int c = (ACH - 1 + k) & (NCH - 1);
        if (k > 0) {
            __syncthreads();
            for (int i = t; i < CHP; i += TB) {
                int pi = c * CHP + i;
                float px = points[pi * 3 + 0], py = points[pi * 3 + 1], pz = points[pi * 3 + 2];
                float pn = __builtin_fmaf(pz, pz, __builtin_fmaf(py, py, px * px));
                sp[i] = make_float4(px, py, pz, pn);
            }
            __syncthreads();
        }
#pragma unroll 2
        for (int s = 0; s < CHP / 64; ++s) {
            float4 p = sp[s * 64 + lane];
            int gidx = c * CHP + s * 64 + lane;
#pragma unroll
            for (int qq = 0; qq < QW; ++qq) {
                float dot = __builtin_fmaf(qz[qq], p.z, __builtin_fmaf(qy[qq], p.y, qx[qq] * p.x));
                float g   = __builtin_fmaf(-2.0f, dot, p.w);
                if (__builtin_expect(g <= tscr[qq], 0)) {
                    int wq = wid * QW + qq;
                    int slot = atomicAdd(&scnt[wq], 1);
                    if (slot < CAP) sidx16[wq * CAP + slot] = (unsigned short)gidx;
                }
            }
        }
    }
    __syncthreads();

    // ---- Phase C: np-exact d2 recompute for candidates, u64 bitonic top-8 ----
    const float4* feats4 = (const float4*)feats;
    float4* outf4 = (float4*)(out + (long)NQ * KNN * 3);
#pragma unroll
    for (int qq = 0; qq < QW; ++qq) {
        int wq = wid * QW + qq;
        int cnt = scnt[wq]; if (cnt > CAP) cnt = CAP;
        unsigned long long key = ~0ull;
        if (lane < cnt) {
            int idx = sidx16[wq * CAP + lane];
            float px = points[idx * 3 + 0], py = points[idx * 3 + 1], pz = points[idx * 3 + 2];
            // np-exact: rounded squares + sequential adds; sgemm K=3 fma chain; (qn-2dot)+pn
            float pn  = (px * px + py * py) + pz * pz;
            float dot = __builtin_fmaf(qz[qq], pz, __builtin_fmaf(qy[qq], py, qx[qq] * px));
            float d2  = (qn[qq] - 2.0f * dot) + pn;
            unsigned b = __float_as_uint(d2);
            unsigned mk = (b & 0x80000000u) ? ~b : (b | 0x80000000u);  // monotone map
            key = ((unsigned long long)mk << 32) | (unsigned)idx;      // (value, stable-index) order
        }
        for (int k2 = 2; k2 <= 64; k2 <<= 1)
            for (int j = k2 >> 1; j > 0; j >>= 1) {
                unsigned lo = __shfl_xor((unsigned)key, j);
                unsigned hi = __shfl_xor((unsigned)(key >> 32), j);
                unsigned long long o = ((unsigned long long)hi << 32) | lo;
                bool keepMin = ((lane & k2) == 0) == ((lane & j) == 0);
                key = ((o < key) == keepMin) ? o : key;
            }
        // lanes 0..7 hold the top-8 ascending. Gather outputs (r5-verified layout).
        int q = qbase + qq;
        int nb = __shfl((int)(unsigned)key, lane >> 3);
        outf4[(long)q * (KNN * FD / 4) + lane] = feats4[(long)nb * (FD / 4) + (lane & 7)];
        int j2 = lane / 3;
        int nb2 = __shfl((int)(unsigned)key, j2);
        if (lane < 24) {
            out[(long)q * (KNN * 3) + lane] = points[nb2 * 3 + (lane - j2 * 3)];
        }
    }
}

extern "C" void kernel_launch(void* const* d_in, const int* in_sizes, int n_in,
                              void* d_out, int out_size, void* d_ws, size_t ws_size,
                              hipStream_t stream) {
    const float* xyz    = (const float*)d_in[0];
    const float* points = (const float*)d_in[1];
    const float* feats  = (const float*)d_in[2];
    float* out = (float*)d_out;
    hipLaunchKernelGGL(knn_kernel, dim3(NQ / QBLK), dim3(TB), 0, stream,
                       xyz, points, feats, out);
}